// Round 16
// baseline (254.848 us; speedup 1.0000x reference)
//
#include <hip/hip_runtime.h>
#include <hip/hip_bf16.h>

#define D  64
#define L  50
#define M  20
#define BB 1024
#define F2 66
#define NEDGE 20000
#define NUSER 100000

typedef __attribute__((ext_vector_type(8))) short bf16x8;
typedef __attribute__((ext_vector_type(4))) float f32x4;

#define MFMA(a,b,c) __builtin_amdgcn_mfma_f32_16x16x32_bf16(a,b,c,0,0,0)

__device__ __forceinline__ short f2bf(float f) {
    union { __hip_bfloat16 h; unsigned short u; } cv;
    cv.h = __float2bfloat16(f);
    return (short)cv.u;
}
__device__ __forceinline__ uint32_t pk2(float a, float b) {
    union { __hip_bfloat162 h; uint32_t u; } cv;
    cv.h.x = __float2bfloat16(a);
    cv.h.y = __float2bfloat16(b);
    return cv.u;
}
__device__ __forceinline__ float bf2f(short s) {
    return __uint_as_float(((uint32_t)(unsigned short)s) << 16);
}
__device__ __forceinline__ float bf2fu(unsigned short s) {
    return __uint_as_float(((uint32_t)s) << 16);
}
__device__ __forceinline__ int swz(int row, int col) {
    return row * 64 + (col ^ ((row & 7) << 3));
}
__device__ __forceinline__ float wsum(float v) {
    #pragma unroll
    for (int off = 32; off > 0; off >>= 1) v += __shfl_xor(v, off);
    return v;
}

// ---------------- weight prep: 12 tblock mats + W2^T + W1^T -> bf16 transposed ----------------

__global__ __launch_bounds__(256) void k_prep(
    const float* __restrict__ qkv, const float* __restrict__ Wo,
    const float* __restrict__ ffW, const float* __restrict__ w2,
    const float* __restrict__ w1, short* __restrict__ wb)
{
    int idx = blockIdx.x * 256 + threadIdx.x;   // 57344 total (224 blocks)
    int mat = idx >> 12, e = idx & 4095;
    int c = e >> 6, k = e & 63;
    const float* src;
    if (mat == 13)      src = w1;
    else if (mat == 12) src = w2;
    else {
        int bi = mat / 6, m = mat % 6;
        if (m < 3)       src = qkv + ((size_t)bi * 3 + m) * 4096;
        else if (m == 3) src = Wo + (size_t)bi * 4096;
        else             src = ffW + ((size_t)bi * 2 + (m - 4)) * 4096;
    }
    wb[(size_t)mat * 4096 + c * 64 + k] = f2bf(src[k * 64 + c]);
}

// ---------------- HGNN layer 1 (MFMA): x[u] = (user_emb[u] + cen_emb[cen[u]]) @ W1 ----------------

__global__ __launch_bounds__(256) void k_hgnn1m(
    const float* __restrict__ user_emb, const float* __restrict__ cen_emb,
    const int* __restrict__ user_cen, const short* __restrict__ w1t,
    unsigned short* __restrict__ xb)
{
    const int tid = threadIdx.x, lane = tid & 63, lo = lane & 15, hg = lane >> 4, w = tid >> 6;
    const int row0 = blockIdx.x * 64 + 16 * w;
    const int arow = row0 + lo;
    const bool av = arow < NUSER;
    const int cidx = av ? user_cen[arow] : 0;

    f32x4 acc[4];
    #pragma unroll
    for (int c = 0; c < 4; ++c) { acc[c][0] = acc[c][1] = acc[c][2] = acc[c][3] = 0.f; }

    #pragma unroll
    for (int ks = 0; ks < 2; ++ks) {
        bf16x8 a;
        if (av) {
            const float4 u0 = *(const float4*)&user_emb[(size_t)arow * 64 + 32 * ks + 8 * hg];
            const float4 u1 = *(const float4*)&user_emb[(size_t)arow * 64 + 32 * ks + 8 * hg + 4];
            const float4 c0 = *(const float4*)&cen_emb[(size_t)cidx * 64 + 32 * ks + 8 * hg];
            const float4 c1 = *(const float4*)&cen_emb[(size_t)cidx * 64 + 32 * ks + 8 * hg + 4];
            uint32_t p0 = pk2(u0.x + c0.x, u0.y + c0.y);
            uint32_t p1 = pk2(u0.z + c0.z, u0.w + c0.w);
            uint32_t p2 = pk2(u1.x + c1.x, u1.y + c1.y);
            uint32_t p3 = pk2(u1.z + c1.z, u1.w + c1.w);
            union { uint32_t u[4]; bf16x8 v; } af;
            af.u[0] = p0; af.u[1] = p1; af.u[2] = p2; af.u[3] = p3;
            a = af.v;
        } else {
            #pragma unroll
            for (int i = 0; i < 8; ++i) a[i] = 0;
        }
        #pragma unroll
        for (int c = 0; c < 4; ++c) {
            bf16x8 bb = *(const bf16x8*)(w1t + (16 * c + lo) * 64 + 32 * ks + 8 * hg);
            acc[c] = MFMA(a, bb, acc[c]);
        }
    }
    #pragma unroll
    for (int c = 0; c < 4; ++c) {
        #pragma unroll
        for (int r = 0; r < 4; ++r) {
            int row = row0 + 4 * hg + r;
            if (row < NUSER) xb[(size_t)row * 64 + 16 * c + lo] = (unsigned short)f2bf(acc[c][r]);
        }
    }
}

// ---------------- edge masked-mean + relu: uint2 gathers, 4 rows per load instr ----------------

__global__ __launch_bounds__(256) void k_edge_gather(
    const unsigned short* __restrict__ xb, const int* __restrict__ seq,
    unsigned short* __restrict__ em)
{
    const int j = threadIdx.x & 63;
    const int e = blockIdx.x * 4 + (threadIdx.x >> 6);   // 5000 blocks * 4 = 20000 edges
    const int s = j >> 4, g = j & 15;
    int my = (j < L) ? seq[(size_t)e * L + j] : 0;
    int cnt = (int)__popcll(__ballot(j < L && my > 0));
    float wv = cnt ? 1.f / (float)cnt : 1.f / (float)L;
    uint2 tv[13];
    bool use[13];
    #pragma unroll
    for (int i = 0; i < 13; ++i) {
        int r = 4 * i + s;
        int rr = (r < L) ? r : 0;
        int idx = __shfl(my, rr);
        use[i] = (r < L) && (cnt ? (idx > 0) : true);
        tv[i] = *(const uint2*)&xb[(size_t)idx * D + 4 * g];
    }
    float a0 = 0.f, a1 = 0.f, a2 = 0.f, a3 = 0.f;
    #pragma unroll
    for (int i = 0; i < 13; ++i) {
        uint32_t lw = tv[i].x, hw = tv[i].y;
        a0 += use[i] ? bf2fu((unsigned short)(lw & 0xffff)) : 0.f;
        a1 += use[i] ? bf2fu((unsigned short)(lw >> 16))    : 0.f;
        a2 += use[i] ? bf2fu((unsigned short)(hw & 0xffff)) : 0.f;
        a3 += use[i] ? bf2fu((unsigned short)(hw >> 16))    : 0.f;
    }
    a0 += __shfl_xor(a0, 16); a0 += __shfl_xor(a0, 32);
    a1 += __shfl_xor(a1, 16); a1 += __shfl_xor(a1, 32);
    a2 += __shfl_xor(a2, 16); a2 += __shfl_xor(a2, 32);
    a3 += __shfl_xor(a3, 16); a3 += __shfl_xor(a3, 32);
    if (s == 0) {
        uint2 o;
        o.x = pk2(fmaxf(a0 * wv, 0.f), fmaxf(a1 * wv, 0.f));
        o.y = pk2(fmaxf(a2 * wv, 0.f), fmaxf(a3 * wv, 0.f));
        *(uint2*)&em[(size_t)e * D + 4 * g] = o;
    }
}

// ---------------- edge2 = em @ W2 (MFMA) ----------------

__global__ __launch_bounds__(256) void k_gemm_edge(
    const unsigned short* __restrict__ em, const short* __restrict__ w2t,
    unsigned short* __restrict__ e2b)
{
    const int tid = threadIdx.x, lane = tid & 63, lo = lane & 15, hg = lane >> 4, w = tid >> 6;
    const int row0 = blockIdx.x * 64 + 16 * w;
    bf16x8 zf;
    #pragma unroll
    for (int i = 0; i < 8; ++i) zf[i] = 0;
    f32x4 acc[4];
    #pragma unroll
    for (int c = 0; c < 4; ++c) { acc[c][0] = acc[c][1] = acc[c][2] = acc[c][3] = 0.f; }
    #pragma unroll
    for (int ks = 0; ks < 2; ++ks) {
        bf16x8 a = zf;
        if (row0 + lo < NEDGE)
            a = *(const bf16x8*)&em[(size_t)(row0 + lo) * D + 32 * ks + 8 * hg];
        #pragma unroll
        for (int c = 0; c < 4; ++c) {
            bf16x8 bb = *(const bf16x8*)(w2t + (16 * c + lo) * 64 + 32 * ks + 8 * hg);
            acc[c] = MFMA(a, bb, acc[c]);
        }
    }
    #pragma unroll
    for (int c = 0; c < 4; ++c) {
        #pragma unroll
        for (int r = 0; r < 4; ++r) {
            int row = row0 + 4 * hg + r;
            if (row < NEDGE) e2b[(size_t)row * D + 16 * c + lo] = (unsigned short)f2bf(acc[c][r]);
        }
    }
}

// ---------------- node masked-mean -> nb (bf16): uint2 gathers, 5 loads for 20 rows ----------------

__global__ __launch_bounds__(256) void k_nodem(
    const unsigned short* __restrict__ e2b, const int* __restrict__ seq,
    const int* __restrict__ useq, const int* __restrict__ data_idx,
    unsigned short* __restrict__ nb)
{
    const int j = threadIdx.x & 63;
    const int w = threadIdx.x >> 6;
    const int p = blockIdx.x * 4 + w;
    const int b = p / L, l = p - b * L;
    const int ib = data_idx[b];
    const int u = seq[(size_t)ib * L + l];
    const int s = j >> 4, g = j & 15;
    int my = (j < M) ? useq[(size_t)u * M + j] : 0;
    int cnt = (int)__popcll(__ballot(j < M && my > 0));
    float wv = cnt ? 1.f / (float)cnt : 1.f / (float)M;
    uint2 tv[5];
    bool use[5];
    #pragma unroll
    for (int i = 0; i < 5; ++i) {
        int r = 4 * i + s;                    // 0..19 exactly
        int idx = __shfl(my, r);
        use[i] = cnt ? (idx > 0) : true;
        tv[i] = *(const uint2*)&e2b[(size_t)idx * D + 4 * g];
    }
    float a0 = 0.f, a1 = 0.f, a2 = 0.f, a3 = 0.f;
    #pragma unroll
    for (int i = 0; i < 5; ++i) {
        uint32_t lw = tv[i].x, hw = tv[i].y;
        a0 += use[i] ? bf2fu((unsigned short)(lw & 0xffff)) : 0.f;
        a1 += use[i] ? bf2fu((unsigned short)(lw >> 16))    : 0.f;
        a2 += use[i] ? bf2fu((unsigned short)(hw & 0xffff)) : 0.f;
        a3 += use[i] ? bf2fu((unsigned short)(hw >> 16))    : 0.f;
    }
    a0 += __shfl_xor(a0, 16); a0 += __shfl_xor(a0, 32);
    a1 += __shfl_xor(a1, 16); a1 += __shfl_xor(a1, 32);
    a2 += __shfl_xor(a2, 16); a2 += __shfl_xor(a2, 32);
    a3 += __shfl_xor(a3, 16); a3 += __shfl_xor(a3, 32);
    if (s == 0) {
        uint2 o;
        o.x = pk2(a0 * wv, a1 * wv);
        o.y = pk2(a2 * wv, a3 * wv);
        *(uint2*)&nb[(size_t)p * D + 4 * g] = o;
    }
}

// ---------------- fused transformer block, BOTH branches, 16 waves (1 head-branch per wave) ----------------
#define XB 0
#define QB 3328
#define KB 6656
#define VBT 9984
#define BRO 14080

__global__ __launch_bounds__(1024, 8) void k_tblock2(
    const unsigned short* __restrict__ nb,
    const int* __restrict__ seq, const int* __restrict__ data_idx,
    const int* __restrict__ timestamps, const int* __restrict__ user_inf,
    const int* __restrict__ user_level,
    const float* __restrict__ time_emb, const float* __restrict__ inf_emb,
    const float* __restrict__ pos_emb,
    const short* __restrict__ wb,
    const float* __restrict__ bo_all, const float* __restrict__ ln_all,
    const float* __restrict__ ffb_all, const float* __restrict__ spread,
    const float* __restrict__ weight, const float* __restrict__ weight2,
    float* __restrict__ n_t, float* __restrict__ n_s)
{
    const int tid = threadIdx.x;
    const int lane = tid & 63, lo = lane & 15, hg = lane >> 4, w = tid >> 6;  // w: 0..15
    const int b = blockIdx.x;
    const int ib = data_idx[b];

    __shared__ __align__(16) short sm[2 * BRO];
    __shared__ float nbuf[2][4][64];
    __shared__ float nvec[2][F2];
    __shared__ int   seqi[52];

    // ---- stage: nb read once -> X_t (branch0) and X_s (branch1) ----
    for (int i = tid; i < 1600; i += 1024) {
        int row = i >> 5, cp = (i & 31) * 2;
        uint32_t nn = *(const uint32_t*)(nb + (size_t)b * 3200 + row * 64 + cp);
        float n0 = bf2fu((unsigned short)(nn & 0xffff));
        float n1 = bf2fu((unsigned short)(nn >> 16));
        int ts  = timestamps[(size_t)ib * L + row];
        int inf = user_inf[(size_t)ib * L + row];
        int lev = user_level[(size_t)ib * L + row];
        float2 te = *(const float2*)(time_emb + (size_t)ts * 64 + cp);
        float2 ie = *(const float2*)(inf_emb + (size_t)inf * 64 + cp);
        float2 pe = *(const float2*)(pos_emb + (size_t)lev * 64 + cp);
        *(uint32_t*)&sm[XB + swz(row, cp)]       = pk2(n0 + te.x, n1 + te.y);
        *(uint32_t*)&sm[BRO + XB + swz(row, cp)] = pk2(n0 + ie.x + pe.x, n1 + ie.y + pe.y);
    }
    if (tid < 52) seqi[tid] = (tid < 50) ? seq[(size_t)ib * L + tid] : 0;
    {
        for (int i = tid; i < 448; i += 1024) {
            ((int*)(sm + XB + 50 * 64))[i] = 0;
            ((int*)(sm + QB + 50 * 64))[i] = 0;
            ((int*)(sm + KB + 50 * 64))[i] = 0;
            ((int*)(sm + BRO + XB + 50 * 64))[i] = 0;
            ((int*)(sm + BRO + QB + 50 * 64))[i] = 0;
            ((int*)(sm + BRO + KB + 50 * 64))[i] = 0;
        }
    }
    __syncthreads();

    // ---- QKV: 24 tasks (br, mat, rt) over 16 waves ----
    #pragma unroll
    for (int t3 = 0; t3 < 2; ++t3) {
        int task = w + 16 * t3;
        if (task < 24) {
            int br  = (task >= 12) ? 1 : 0;
            int rem = task - 12 * br;
            int mat = rem >> 2, rt = rem & 3;
            const int RB = br * BRO;
            const short* WTb = wb + (size_t)br * 6 * 4096 + (size_t)mat * 4096;
            f32x4 a4[4];
            #pragma unroll
            for (int c = 0; c < 4; ++c) { a4[c][0] = a4[c][1] = a4[c][2] = a4[c][3] = 0.f; }
            #pragma unroll
            for (int ks = 0; ks < 2; ++ks) {
                bf16x8 xa = *(const bf16x8*)&sm[RB + XB + swz(16 * rt + lo, 32 * ks + 8 * hg)];
                #pragma unroll
                for (int c = 0; c < 4; ++c) {
                    bf16x8 bb = *(const bf16x8*)(WTb + (16 * c + lo) * 64 + 32 * ks + 8 * hg);
                    a4[c] = MFMA(xa, bb, a4[c]);
                }
            }
            if (mat == 0) {
                #pragma unroll
                for (int c = 0; c < 4; ++c)
                    #pragma unroll
                    for (int r = 0; r < 4; ++r) {
                        int row = 16 * rt + 4 * hg + r;
                        if (row < 52)
                            sm[RB + QB + swz(row, 16 * c + lo)] = f2bf(a4[c][r] * 0.35355339059327378f);
                    }
            } else if (mat == 1) {
                #pragma unroll
                for (int c = 0; c < 4; ++c)
                    #pragma unroll
                    for (int r = 0; r < 4; ++r) {
                        int row = 16 * rt + 4 * hg + r;
                        if (row < 52) sm[RB + KB + swz(row, 16 * c + lo)] = f2bf(a4[c][r]);
                    }
            } else {
                #pragma unroll
                for (int c = 0; c < 4; ++c)
                    #pragma unroll
                    for (int r = 0; r < 4; ++r) {
                        int row = 16 * rt + 4 * hg + r, col = 16 * c + lo;
                        sm[RB + VBT + swz(col, row)] = (row < 50) ? f2bf(a4[c][r]) : (short)0;
                    }
            }
        }
    }
    __syncthreads();

    int svl = (lane < 50) ? seqi[lane] : 0;
    int cnt = (int)__popcll(__ballot(svl > 0));
    float msel[4][4];
    #pragma unroll
    for (int mt = 0; mt < 4; ++mt) {
        #pragma unroll
        for (int r = 0; r < 4; ++r) {
            int m = 16 * mt + 4 * hg + r;
            msel[mt][r] = (m < 50) ? ((seqi[m] > 0) ? 0.f : -1e9f) : -3.0e38f;
        }
    }

    bf16x8 zf;
    #pragma unroll
    for (int i = 0; i < 8; ++i) zf[i] = 0;

    // ---- attention: wave w -> branch w>>3, head w&7 (ONE task per wave) ----
    f32x4 ctx[4];
    const int abr = w >> 3, hd = w & 7;
    {
        const int RB = abr * BRO;
        bf16x8 ka[4], qf[4];
        #pragma unroll
        for (int t = 0; t < 4; ++t) {
            ka[t] = zf; qf[t] = zf;
            if (hg == 0) {
                ka[t] = *(const bf16x8*)&sm[RB + KB + swz(16 * t + lo, hd * 8)];
                qf[t] = *(const bf16x8*)&sm[RB + QB + swz(16 * t + lo, hd * 8)];
            }
        }
        f32x4 s[4][4];
        __builtin_amdgcn_s_setprio(1);
        #pragma unroll
        for (int mt = 0; mt < 4; ++mt) {
            #pragma unroll
            for (int c = 0; c < 4; ++c) {
                f32x4 z; z[0] = z[1] = z[2] = z[3] = 0.f;
                s[mt][c] = MFMA(ka[mt], qf[c], z);
            }
        }
        __builtin_amdgcn_s_setprio(0);
        #pragma unroll
        for (int mt = 0; mt < 4; ++mt) {
            #pragma unroll
            for (int r = 0; r < 4; ++r) {
                float ms = msel[mt][r];
                bool valid = (ms == 0.f);
                #pragma unroll
                for (int c = 0; c < 4; ++c) s[mt][c][r] = valid ? s[mt][c][r] : ms;
            }
        }
        uint32_t pk[4][4][2];
        #pragma unroll
        for (int c = 0; c < 4; ++c) {
            float mx = -3.4e38f;
            #pragma unroll
            for (int mt = 0; mt < 4; ++mt) {
                #pragma unroll
                for (int r = 0; r < 4; ++r) mx = fmaxf(mx, s[mt][c][r]);
            }
            mx = fmaxf(mx, __shfl_xor(mx, 16));
            mx = fmaxf(mx, __shfl_xor(mx, 32));
            float den = 0.f;
            #pragma unroll
            for (int mt = 0; mt < 4; ++mt) {
                #pragma unroll
                for (int r = 0; r < 4; ++r) {
                    float e = __expf(s[mt][c][r] - mx);
                    s[mt][c][r] = e; den += e;
                }
            }
            den += __shfl_xor(den, 16);
            den += __shfl_xor(den, 32);
            float inv = 1.f / den;
            #pragma unroll
            for (int mt = 0; mt < 4; ++mt) {
                pk[mt][c][0] = pk2(s[mt][c][0] * inv, s[mt][c][1] * inv);
                pk[mt][c][1] = pk2(s[mt][c][2] * inv, s[mt][c][3] * inv);
            }
        }
        #pragma unroll
        for (int t = 0; t < 4; ++t) { ctx[t][0] = ctx[t][1] = ctx[t][2] = ctx[t][3] = 0.f; }
        // PV: A-frag rebuilt via in-wave lane permutation (no LDS scratch)
        __builtin_amdgcn_s_setprio(1);
        #pragma unroll
        for (int rt = 0; rt < 4; ++rt) {
            #pragma unroll
            for (int ks = 0; ks < 2; ++ks) {
                union { uint32_t u[4]; bf16x8 v; } af;
                #pragma unroll
                for (int j = 0; j < 4; ++j) {
                    int src = lo + 16 * (2 * (hg & 1) + (j >> 1));
                    uint32_t a0 = __shfl(pk[2 * ks][rt][j & 1], src);
                    uint32_t a1 = __shfl(pk[2 * ks + 1][rt][j & 1], src);
                    af.u[j] = (hg < 2) ? a0 : a1;
                }
                bf16x8 bfr = zf;
                if (lo < 8) bfr = *(const bf16x8*)&sm[RB + VBT + swz(hd * 8 + lo, 32 * ks + 8 * hg)];
                ctx[rt] = MFMA(af.v, bfr, ctx[rt]);
            }
        }
        __builtin_amdgcn_s_setprio(0);
    }
    __syncthreads();   // all K/Q/V LDS reads done before ctx overwrites KB
    if (lo < 8) {
        const int RB = abr * BRO;
        #pragma unroll
        for (int rt = 0; rt < 4; ++rt) {
            #pragma unroll
            for (int r = 0; r < 4; ++r) {
                int row = 16 * rt + 4 * hg + r;
                if (row < 52) sm[RB + KB + swz(row, hd * 8 + lo)] = f2bf(ctx[rt][r]);
            }
        }
    }
    __syncthreads();

    // ---- epilogue: waves 0-7 (wave w -> branch w>>2, stripe w&3); waves 8-15 idle ----
    if (w < 8) {
        const int ebr = w >> 2, ws = w & 3;
        const int RB = ebr * BRO;
        const short* WT  = wb + (size_t)ebr * 6 * 4096;
        const float* bo  = bo_all + ebr * 64;
        const float* lnp = ln_all + ebr * 256;
        const float* ffb = ffb_all + ebr * 128;

        float g1[4], b1[4], g2[4], b2[4], boc[4], f1b[4], f2b[4];
        #pragma unroll
        for (int c = 0; c < 4; ++c) {
            int col = 16 * c + lo;
            g1[c] = lnp[col];        b1[c] = lnp[64 + col];
            g2[c] = lnp[128 + col];  b2[c] = lnp[192 + col];
            boc[c] = bo[col]; f1b[c] = ffb[col]; f2b[c] = ffb[64 + col];
        }

        f32x4 acc[4];
        #pragma unroll
        for (int c = 0; c < 4; ++c) { acc[c][0] = acc[c][1] = acc[c][2] = acc[c][3] = 0.f; }
        #pragma unroll
        for (int ks = 0; ks < 2; ++ks) {
            bf16x8 a = *(const bf16x8*)&sm[RB + KB + swz(16 * ws + lo, 32 * ks + 8 * hg)]; // ctx
            #pragma unroll
            for (int c = 0; c < 4; ++c) {
                bf16x8 bb = *(const bf16x8*)(WT + 3 * 4096 + (16 * c + lo) * 64 + 32 * ks + 8 * hg);
                acc[c] = MFMA(a, bb, acc[c]);
            }
        }
        float x1v[4][4];
        #pragma unroll
        for (int r = 0; r < 4; ++r) {
            int row = 16 * ws + 4 * hg + r;
            float t0 = bf2f(sm[RB + XB + swz(row, lo)])      + acc[0][r] + boc[0];
            float t1 = bf2f(sm[RB + XB + swz(row, 16 + lo)]) + acc[1][r] + boc[1];
            float t2 = bf2f(sm[RB + XB + swz(row, 32 + lo)]) + acc[2][r] + boc[2];
            float t3 = bf2f(sm[RB + XB + swz(row, 48 + lo)]) + acc[3][r] + boc[3];
            float s1 = t0 + t1 + t2 + t3;
            float q1 = t0 * t0 + t1 * t1 + t2 * t2 + t3 * t3;
            #pragma unroll
            for (int d = 1; d <= 8; d <<= 1) { s1 += __shfl_xor(s1, d); q1 += __shfl_xor(q1, d); }
            float mean = s1 * 0.015625f;
            float var = q1 * 0.015625f - mean * mean;
            float rin = rsqrtf(var + 1e-5f);
            float x0 = (t0 - mean) * rin * g1[0] + b1[0];
            float x1 = (t1 - mean) * rin * g1[1] + b1[1];
            float x2 = (t2 - mean) * rin * g1[2] + b1[2];
            float x3 = (t3 - mean) * rin * g1[3] + b1[3];
            x1v[0][r] = x0; x1v[1][r] = x1; x1v[2][r] = x2; x1v[3][r] = x3;
            if (row < 52) {
                sm[RB + QB + swz(row, lo)]      = f2bf(x0);
                sm[RB + QB + swz(row, 16 + lo)] = f2bf(x1);
                sm[RB + QB + swz(row, 32 + lo)] = f2bf(x2);
                sm[RB + QB + swz(row, 48 + lo)] = f2bf(x3);
            }
        }
        #pragma unroll
        for (int c = 0; c < 4; ++c) { acc[c][0] = acc[c][1] = acc[c][2] = acc[c][3] = 0.f; }
        #pragma unroll
        for (int ks = 0; ks < 2; ++ks) {
            bf16x8 a = *(const bf16x8*)&sm[RB + QB + swz(16 * ws + lo, 32 * ks + 8 * hg)];
            #pragma unroll
            for (int c = 0; c < 4; ++c) {
                bf16x8 bb = *(const bf16x8*)(WT + 4 * 4096 + (16 * c + lo) * 64 + 32 * ks + 8 * hg);
                acc[c] = MFMA(a, bb, acc[c]);
            }
        }
        #pragma unroll
        for (int c = 0; c < 4; ++c) {
            #pragma unroll
            for (int r = 0; r < 4; ++r) {
                int row = 16 * ws + 4 * hg + r;
                if (row < 52) sm[RB + KB + swz(row, 16 * c + lo)] = f2bf(fmaxf(acc[c][r] + f1b[c], 0.f));
            }
        }
        #pragma unroll
        for (int c = 0; c < 4; ++c) { acc[c][0] = acc[c][1] = acc[c][2] = acc[c][3] = 0.f; }
        #pragma unroll
        for (int ks = 0; ks < 2; ++ks) {
            bf16x8 a = *(const bf16x8*)&sm[RB + KB + swz(16 * ws + lo, 32 * ks + 8 * hg)];
            #pragma unroll
            for (int c = 0; c < 4; ++c) {
                bf16x8 bb = *(const bf16x8*)(WT + 5 * 4096 + (16 * c + lo) * 64 + 32 * ks + 8 * hg);
                acc[c] = MFMA(a, bb, acc[c]);
            }
        }
        float wv = (cnt > 0) ? 1.f / (float)cnt : 0.02f;
        float np[4] = {0.f, 0.f, 0.f, 0.f};
        #pragma unroll
        for (int r = 0; r < 4; ++r) {
            int row = 16 * ws + 4 * hg + r;
            float t0 = x1v[0][r] + acc[0][r] + f2b[0];
            float t1 = x1v[1][r] + acc[1][r] + f2b[1];
            float t2 = x1v[2][r] + acc[2][r] + f2b[2];
            float t3 = x1v[3][r] + acc[3][r] + f2b[3];
            float s1 = t0 + t1 + t2 + t3;
            float q1 = t0 * t0 + t1 * t1 + t2 * t2 + t3 * t3;
            #pragma unroll
            for (int d = 1; d <= 8; d <<= 1) { s1 += __shfl_xor(s1, d); q1 += __shfl_xor(q1, d); }
            float mean = s1 * 0.015625f;
            float var = q1 * 0.015625f - mean * mean;
            float rin = rsqrtf(var + 1e-5f);
            float wl = 0.f;
            if (row < 50) {
                int sv = seqi[row];
                wl = (cnt > 0) ? ((sv > 0) ? wv : 0.f) : wv;
            }
            np[0] += ((t0 - mean) * rin * g2[0] + b2[0]) * wl;
            np[1] += ((t1 - mean) * rin * g2[1] + b2[1]) * wl;
            np[2] += ((t2 - mean) * rin * g2[2] + b2[2]) * wl;
            np[3] += ((t3 - mean) * rin * g2[3] + b2[3]) * wl;
        }
        #pragma unroll
        for (int c = 0; c < 4; ++c) {
            np[c] += __shfl_xor(np[c], 16);
            np[c] += __shfl_xor(np[c], 32);
        }
        if (hg == 0) {
            #pragma unroll
            for (int c = 0; c < 4; ++c) nbuf[ebr][ws][16 * c + lo] = np[c];
        }
    }
    __syncthreads();
    if (tid < 64)
        nvec[0][tid] = nbuf[0][0][tid] + nbuf[0][1][tid] + nbuf[0][2][tid] + nbuf[0][3][tid];
    else if (tid < 128)
        nvec[1][tid - 64] = nbuf[1][0][tid - 64] + nbuf[1][1][tid - 64] +
                            nbuf[1][2][tid - 64] + nbuf[1][3][tid - 64];
    else if (tid == 128) nvec[0][64] = spread[(size_t)ib * 4 + 2] * (1.f / 86400.f);
    else if (tid == 129) nvec[0][65] = spread[(size_t)ib * 4 + 3] * (1.f / 86400.f);
    else if (tid == 130) nvec[1][64] = spread[(size_t)ib * 4 + 0];
    else if (tid == 131) nvec[1][65] = spread[(size_t)ib * 4 + 1];
    __syncthreads();
    if (tid < F2) {
        float a = 0.f;
        for (int k = 0; k < F2; ++k) a += nvec[0][k] * weight[k * F2 + tid];
        n_t[(size_t)b * F2 + tid] = a;
    } else if (tid >= 128 && tid < 128 + F2) {
        int col = tid - 128;
        float a = 0.f;
        for (int k = 0; k < F2; ++k) a += nvec[1][k] * weight2[k * F2 + col];
        n_s[(size_t)b * F2 + col] = a;
    }
}

// ---------------- gated fusion head: 4 batch elems per block, wave-local ----------------

__global__ __launch_bounds__(256) void k_fuse(
    const float* __restrict__ n_t, const float* __restrict__ n_s,
    const float* __restrict__ l1W, const float* __restrict__ l1b,
    const float* __restrict__ l2W, const float* __restrict__ l2b,
    const float* __restrict__ outW, const float* __restrict__ outb,
    float* __restrict__ out)
{
    const int w = threadIdx.x >> 6, j = threadIdx.x & 63;
    const int b = blockIdx.x * 4 + w;
    __shared__ float et[4][F2], es[4][F2], fused[4][F2];
    for (int t = j; t < F2; t += 64) { et[w][t] = n_t[(size_t)b * F2 + t]; es[w][t] = n_s[(size_t)b * F2 + t]; }
    float sl[2];
    for (int s = 0; s < 2; ++s) {
        const float* e = s ? es[w] : et[w];
        float part = 0.f;
        for (int t = j; t < F2; t += 64) {
            float acc = l1b[t];
            for (int k = 0; k < F2; ++k) acc += e[k] * l1W[k * F2 + t];
            part += tanhf(acc) * l2W[t];
        }
        part = wsum(part);
        sl[s] = part + l2b[0];
    }
    float mx = fmaxf(sl[0], sl[1]);
    float e0 = __expf(sl[0] - mx), e1 = __expf(sl[1] - mx);
    float inv = 1.f / (e0 + e1);
    float sc0 = e0 * inv, sc1 = e1 * inv;
    for (int t = j; t < F2; t += 64) fused[w][t] = sc0 * et[w][t] + sc1 * es[w][t];
    float p0 = 0.f, p1 = 0.f;
    for (int t = j; t < F2; t += 64) {
        p0 += fused[w][t] * outW[t * 2 + 0];
        p1 += fused[w][t] * outW[t * 2 + 1];
    }
    p0 = wsum(p0); p1 = wsum(p1);
    if (j == 0) {
        float l0 = p0 + outb[0], l1v = p1 + outb[1];
        float m = fmaxf(l0, l1v);
        float lse = m + logf(__expf(l0 - m) + __expf(l1v - m));
        out[(size_t)b * 2 + 0] = l0 - lse;
        out[(size_t)b * 2 + 1] = l1v - lse;
    }
}

extern "C" void kernel_launch(void* const* d_in, const int* in_sizes, int n_in,
                              void* d_out, int out_size, void* d_ws, size_t ws_size,
                              hipStream_t stream)
{
    (void)in_sizes; (void)n_in; (void)out_size; (void)ws_size;
    const float* user_emb = (const float*)d_in[0];
    const float* cen_emb  = (const float*)d_in[1];
    const float* time_emb = (const float*)d_in[2];
    const float* pos_emb  = (const float*)d_in[3];
    const float* inf_emb  = (const float*)d_in[4];
    const float* w1       = (const float*)d_in[5];
    const float* w2       = (const float*)d_in[6];
    const float* weight   = (const float*)d_in[10];
    const float* weight2  = (const float*)d_in[11];
    const float* l1W      = (const float*)d_in[12];
    const float* l1b      = (const float*)d_in[13];
    const float* l2W      = (const float*)d_in[14];
    const float* l2b      = (const float*)d_in[15];
    const float* outW     = (const float*)d_in[16];
    const float* outb     = (const float*)d_in[17];
    const float* qkv      = (const float*)d_in[18];
    const float* Wo       = (const float*)d_in[19];
    const float* bo       = (const float*)d_in[20];
    const float* lnp      = (const float*)d_in[21];
    const float* ffW      = (const float*)d_in[22];
    const float* ffb      = (const float*)d_in[23];
    const float* spread   = (const float*)d_in[25];
    const int* data_idx   = (const int*)d_in[26];
    const int* seq        = (const int*)d_in[27];
    const int* timestamps = (const int*)d_in[28];
    const int* user_level = (const int*)d_in[29];
    const int* useq       = (const int*)d_in[30];
    const int* user_inf   = (const int*)d_in[31];
    const int* user_cen   = (const int*)d_in[32];

    // workspace layout (ushort units)
    unsigned short* wbt = (unsigned short*)d_ws;          // 14*4096 = 57,344
    unsigned short* xb  = wbt + 57344;                    // 6,400,000
    unsigned short* em  = xb + 6400000;                   // 1,280,000
    unsigned short* e2b = em + 1280000;                   // 1,280,000
    unsigned short* nbm = e2b + 1280000;                  // 3,276,800
    float* n_t = (float*)(nbm + 3276800);                 // 67,584 f32
    float* n_s = n_t + 67584;                             // 67,584 f32
    float* out = (float*)d_out;

    k_prep<<<224, 256, 0, stream>>>(qkv, Wo, ffW, w2, w1, (short*)wbt);
    k_hgnn1m<<<1563, 256, 0, stream>>>(user_emb, cen_emb, user_cen,
                                       (const short*)wbt + 13 * 4096, xb);
    k_edge_gather<<<5000, 256, 0, stream>>>(xb, seq, em);
    k_gemm_edge<<<313, 256, 0, stream>>>(em, (const short*)wbt + 12 * 4096, e2b);
    k_nodem<<<12800, 256, 0, stream>>>(e2b, seq, useq, data_idx, nbm);
    k_tblock2<<<1024, 1024, 0, stream>>>(nbm, seq, data_idx, timestamps, user_inf,
                                         user_level, time_emb, inf_emb, pos_emb,
                                         (const short*)wbt, bo, lnp, ffb, spread,
                                         weight, weight2, n_t, n_s);
    k_fuse<<<256, 256, 0, stream>>>(n_t, n_s, l1W, l1b, l2W, l2b, outW, outb, out);
}

// Round 17
// 163.207 us; speedup vs baseline: 1.5615x; 1.5615x over previous
//
#include <hip/hip_runtime.h>
#include <hip/hip_bf16.h>

#define D  64
#define L  50
#define M  20
#define BB 1024
#define F2 66
#define NEDGE 20000
#define NUSER 100000

typedef __attribute__((ext_vector_type(8))) short bf16x8;
typedef __attribute__((ext_vector_type(4))) float f32x4;

#define MFMA(a,b,c) __builtin_amdgcn_mfma_f32_16x16x32_bf16(a,b,c,0,0,0)

__device__ __forceinline__ short f2bf(float f) {
    union { __hip_bfloat16 h; unsigned short u; } cv;
    cv.h = __float2bfloat16(f);
    return (short)cv.u;
}
__device__ __forceinline__ uint32_t pk2(float a, float b) {
    union { __hip_bfloat162 h; uint32_t u; } cv;
    cv.h.x = __float2bfloat16(a);
    cv.h.y = __float2bfloat16(b);
    return cv.u;
}
__device__ __forceinline__ float bf2f(short s) {
    return __uint_as_float(((uint32_t)(unsigned short)s) << 16);
}
__device__ __forceinline__ float bf2fu(unsigned short s) {
    return __uint_as_float(((uint32_t)s) << 16);
}
__device__ __forceinline__ int swz(int row, int col) {
    return row * 64 + (col ^ ((row & 7) << 3));
}
__device__ __forceinline__ float wsum(float v) {
    #pragma unroll
    for (int off = 32; off > 0; off >>= 1) v += __shfl_xor(v, off);
    return v;
}

// ---------------- weight prep: 12 tblock mats + W2^T + W1^T -> bf16 transposed ----------------

__global__ __launch_bounds__(256) void k_prep(
    const float* __restrict__ qkv, const float* __restrict__ Wo,
    const float* __restrict__ ffW, const float* __restrict__ w2,
    const float* __restrict__ w1, short* __restrict__ wb)
{
    int idx = blockIdx.x * 256 + threadIdx.x;   // 57344 total (224 blocks)
    int mat = idx >> 12, e = idx & 4095;
    int c = e >> 6, k = e & 63;
    const float* src;
    if (mat == 13)      src = w1;
    else if (mat == 12) src = w2;
    else {
        int bi = mat / 6, m = mat % 6;
        if (m < 3)       src = qkv + ((size_t)bi * 3 + m) * 4096;
        else if (m == 3) src = Wo + (size_t)bi * 4096;
        else             src = ffW + ((size_t)bi * 2 + (m - 4)) * 4096;
    }
    wb[(size_t)mat * 4096 + c * 64 + k] = f2bf(src[k * 64 + c]);
}

// ---------------- HGNN layer 1 (MFMA): x[u] = (user_emb[u] + cen_emb[cen[u]]) @ W1 ----------------

__global__ __launch_bounds__(256) void k_hgnn1m(
    const float* __restrict__ user_emb, const float* __restrict__ cen_emb,
    const int* __restrict__ user_cen, const short* __restrict__ w1t,
    unsigned short* __restrict__ xb)
{
    const int tid = threadIdx.x, lane = tid & 63, lo = lane & 15, hg = lane >> 4, w = tid >> 6;
    const int row0 = blockIdx.x * 64 + 16 * w;
    const int arow = row0 + lo;
    const bool av = arow < NUSER;
    const int cidx = av ? user_cen[arow] : 0;

    f32x4 acc[4];
    #pragma unroll
    for (int c = 0; c < 4; ++c) { acc[c][0] = acc[c][1] = acc[c][2] = acc[c][3] = 0.f; }

    #pragma unroll
    for (int ks = 0; ks < 2; ++ks) {
        bf16x8 a;
        if (av) {
            const float4 u0 = *(const float4*)&user_emb[(size_t)arow * 64 + 32 * ks + 8 * hg];
            const float4 u1 = *(const float4*)&user_emb[(size_t)arow * 64 + 32 * ks + 8 * hg + 4];
            const float4 c0 = *(const float4*)&cen_emb[(size_t)cidx * 64 + 32 * ks + 8 * hg];
            const float4 c1 = *(const float4*)&cen_emb[(size_t)cidx * 64 + 32 * ks + 8 * hg + 4];
            uint32_t p0 = pk2(u0.x + c0.x, u0.y + c0.y);
            uint32_t p1 = pk2(u0.z + c0.z, u0.w + c0.w);
            uint32_t p2 = pk2(u1.x + c1.x, u1.y + c1.y);
            uint32_t p3 = pk2(u1.z + c1.z, u1.w + c1.w);
            union { uint32_t u[4]; bf16x8 v; } af;
            af.u[0] = p0; af.u[1] = p1; af.u[2] = p2; af.u[3] = p3;
            a = af.v;
        } else {
            #pragma unroll
            for (int i = 0; i < 8; ++i) a[i] = 0;
        }
        #pragma unroll
        for (int c = 0; c < 4; ++c) {
            bf16x8 bb = *(const bf16x8*)(w1t + (16 * c + lo) * 64 + 32 * ks + 8 * hg);
            acc[c] = MFMA(a, bb, acc[c]);
        }
    }
    #pragma unroll
    for (int c = 0; c < 4; ++c) {
        #pragma unroll
        for (int r = 0; r < 4; ++r) {
            int row = row0 + 4 * hg + r;
            if (row < NUSER) xb[(size_t)row * 64 + 16 * c + lo] = (unsigned short)f2bf(acc[c][r]);
        }
    }
}

// ---------------- edge masked-mean + relu: uint2 gathers, 4 rows per load instr ----------------

__global__ __launch_bounds__(256) void k_edge_gather(
    const unsigned short* __restrict__ xb, const int* __restrict__ seq,
    unsigned short* __restrict__ em)
{
    const int j = threadIdx.x & 63;
    const int e = blockIdx.x * 4 + (threadIdx.x >> 6);   // 5000 blocks * 4 = 20000 edges
    const int s = j >> 4, g = j & 15;
    int my = (j < L) ? seq[(size_t)e * L + j] : 0;
    int cnt = (int)__popcll(__ballot(j < L && my > 0));
    float wv = cnt ? 1.f / (float)cnt : 1.f / (float)L;
    uint2 tv[13];
    bool use[13];
    #pragma unroll
    for (int i = 0; i < 13; ++i) {
        int r = 4 * i + s;
        int rr = (r < L) ? r : 0;
        int idx = __shfl(my, rr);
        use[i] = (r < L) && (cnt ? (idx > 0) : true);
        tv[i] = *(const uint2*)&xb[(size_t)idx * D + 4 * g];
    }
    float a0 = 0.f, a1 = 0.f, a2 = 0.f, a3 = 0.f;
    #pragma unroll
    for (int i = 0; i < 13; ++i) {
        uint32_t lw = tv[i].x, hw = tv[i].y;
        a0 += use[i] ? bf2fu((unsigned short)(lw & 0xffff)) : 0.f;
        a1 += use[i] ? bf2fu((unsigned short)(lw >> 16))    : 0.f;
        a2 += use[i] ? bf2fu((unsigned short)(hw & 0xffff)) : 0.f;
        a3 += use[i] ? bf2fu((unsigned short)(hw >> 16))    : 0.f;
    }
    a0 += __shfl_xor(a0, 16); a0 += __shfl_xor(a0, 32);
    a1 += __shfl_xor(a1, 16); a1 += __shfl_xor(a1, 32);
    a2 += __shfl_xor(a2, 16); a2 += __shfl_xor(a2, 32);
    a3 += __shfl_xor(a3, 16); a3 += __shfl_xor(a3, 32);
    if (s == 0) {
        uint2 o;
        o.x = pk2(fmaxf(a0 * wv, 0.f), fmaxf(a1 * wv, 0.f));
        o.y = pk2(fmaxf(a2 * wv, 0.f), fmaxf(a3 * wv, 0.f));
        *(uint2*)&em[(size_t)e * D + 4 * g] = o;
    }
}

// ---------------- edge2 = em @ W2 (MFMA) ----------------

__global__ __launch_bounds__(256) void k_gemm_edge(
    const unsigned short* __restrict__ em, const short* __restrict__ w2t,
    unsigned short* __restrict__ e2b)
{
    const int tid = threadIdx.x, lane = tid & 63, lo = lane & 15, hg = lane >> 4, w = tid >> 6;
    const int row0 = blockIdx.x * 64 + 16 * w;
    bf16x8 zf;
    #pragma unroll
    for (int i = 0; i < 8; ++i) zf[i] = 0;
    f32x4 acc[4];
    #pragma unroll
    for (int c = 0; c < 4; ++c) { acc[c][0] = acc[c][1] = acc[c][2] = acc[c][3] = 0.f; }
    #pragma unroll
    for (int ks = 0; ks < 2; ++ks) {
        bf16x8 a = zf;
        if (row0 + lo < NEDGE)
            a = *(const bf16x8*)&em[(size_t)(row0 + lo) * D + 32 * ks + 8 * hg];
        #pragma unroll
        for (int c = 0; c < 4; ++c) {
            bf16x8 bb = *(const bf16x8*)(w2t + (16 * c + lo) * 64 + 32 * ks + 8 * hg);
            acc[c] = MFMA(a, bb, acc[c]);
        }
    }
    #pragma unroll
    for (int c = 0; c < 4; ++c) {
        #pragma unroll
        for (int r = 0; r < 4; ++r) {
            int row = row0 + 4 * hg + r;
            if (row < NEDGE) e2b[(size_t)row * D + 16 * c + lo] = (unsigned short)f2bf(acc[c][r]);
        }
    }
}

// ---------------- node masked-mean -> nb (bf16): uint2 gathers, 5 loads for 20 rows ----------------

__global__ __launch_bounds__(256) void k_nodem(
    const unsigned short* __restrict__ e2b, const int* __restrict__ seq,
    const int* __restrict__ useq, const int* __restrict__ data_idx,
    unsigned short* __restrict__ nb)
{
    const int j = threadIdx.x & 63;
    const int w = threadIdx.x >> 6;
    const int p = blockIdx.x * 4 + w;
    const int b = p / L, l = p - b * L;
    const int ib = data_idx[b];
    const int u = seq[(size_t)ib * L + l];
    const int s = j >> 4, g = j & 15;
    int my = (j < M) ? useq[(size_t)u * M + j] : 0;
    int cnt = (int)__popcll(__ballot(j < M && my > 0));
    float wv = cnt ? 1.f / (float)cnt : 1.f / (float)M;
    uint2 tv[5];
    bool use[5];
    #pragma unroll
    for (int i = 0; i < 5; ++i) {
        int r = 4 * i + s;                    // 0..19 exactly
        int idx = __shfl(my, r);
        use[i] = cnt ? (idx > 0) : true;
        tv[i] = *(const uint2*)&e2b[(size_t)idx * D + 4 * g];
    }
    float a0 = 0.f, a1 = 0.f, a2 = 0.f, a3 = 0.f;
    #pragma unroll
    for (int i = 0; i < 5; ++i) {
        uint32_t lw = tv[i].x, hw = tv[i].y;
        a0 += use[i] ? bf2fu((unsigned short)(lw & 0xffff)) : 0.f;
        a1 += use[i] ? bf2fu((unsigned short)(lw >> 16))    : 0.f;
        a2 += use[i] ? bf2fu((unsigned short)(hw & 0xffff)) : 0.f;
        a3 += use[i] ? bf2fu((unsigned short)(hw >> 16))    : 0.f;
    }
    a0 += __shfl_xor(a0, 16); a0 += __shfl_xor(a0, 32);
    a1 += __shfl_xor(a1, 16); a1 += __shfl_xor(a1, 32);
    a2 += __shfl_xor(a2, 16); a2 += __shfl_xor(a2, 32);
    a3 += __shfl_xor(a3, 16); a3 += __shfl_xor(a3, 32);
    if (s == 0) {
        uint2 o;
        o.x = pk2(a0 * wv, a1 * wv);
        o.y = pk2(a2 * wv, a3 * wv);
        *(uint2*)&nb[(size_t)p * D + 4 * g] = o;
    }
}

// ---------------- fused transformer block, BOTH branches per block, 8 waves ----------------
#define XB 0
#define QB 3328
#define KB 6656
#define VBT 9984
#define BRO 14080
#define PB  28160

__global__ __launch_bounds__(512, 4) void k_tblock2(
    const unsigned short* __restrict__ nb,
    const int* __restrict__ seq, const int* __restrict__ data_idx,
    const int* __restrict__ timestamps, const int* __restrict__ user_inf,
    const int* __restrict__ user_level,
    const float* __restrict__ time_emb, const float* __restrict__ inf_emb,
    const float* __restrict__ pos_emb,
    const short* __restrict__ wb,
    const float* __restrict__ bo_all, const float* __restrict__ ln_all,
    const float* __restrict__ ffb_all, const float* __restrict__ spread,
    const float* __restrict__ weight, const float* __restrict__ weight2,
    float* __restrict__ n_t, float* __restrict__ n_s)
{
    const int tid = threadIdx.x;
    const int lane = tid & 63, lo = lane & 15, hg = lane >> 4, w = tid >> 6;  // w: 0..7
    const int b = blockIdx.x;
    const int ib = data_idx[b];

    __shared__ __align__(16) short sm[36352];
    __shared__ float nbuf[2][4][64];
    __shared__ float nvec[2][F2];
    __shared__ int   seqi[52];

    // ---- stage: nb read once -> X_t (branch0) and X_s (branch1) ----
    for (int i = tid; i < 1600; i += 512) {
        int row = i >> 5, cp = (i & 31) * 2;
        uint32_t nn = *(const uint32_t*)(nb + (size_t)b * 3200 + row * 64 + cp);
        float n0 = bf2fu((unsigned short)(nn & 0xffff));
        float n1 = bf2fu((unsigned short)(nn >> 16));
        int ts  = timestamps[(size_t)ib * L + row];
        int inf = user_inf[(size_t)ib * L + row];
        int lev = user_level[(size_t)ib * L + row];
        float2 te = *(const float2*)(time_emb + (size_t)ts * 64 + cp);
        float2 ie = *(const float2*)(inf_emb + (size_t)inf * 64 + cp);
        float2 pe = *(const float2*)(pos_emb + (size_t)lev * 64 + cp);
        *(uint32_t*)&sm[XB + swz(row, cp)]       = pk2(n0 + te.x, n1 + te.y);
        *(uint32_t*)&sm[BRO + XB + swz(row, cp)] = pk2(n0 + ie.x + pe.x, n1 + ie.y + pe.y);
    }
    if (tid < 52) seqi[tid] = (tid < 50) ? seq[(size_t)ib * L + tid] : 0;
    {
        for (int i = tid; i < 448; i += 512) {
            ((int*)(sm + XB + 50 * 64))[i] = 0;
            ((int*)(sm + QB + 50 * 64))[i] = 0;
            ((int*)(sm + KB + 50 * 64))[i] = 0;
            ((int*)(sm + BRO + XB + 50 * 64))[i] = 0;
            ((int*)(sm + BRO + QB + 50 * 64))[i] = 0;
            ((int*)(sm + BRO + KB + 50 * 64))[i] = 0;
        }
    }
    __syncthreads();

    // ---- QKV: 24 tasks (br, mat, rt) over 8 waves, 3 each ----
    #pragma unroll
    for (int t3 = 0; t3 < 3; ++t3) {
        int task = w + 8 * t3;
        int br  = (task >= 12) ? 1 : 0;
        int rem = task - 12 * br;
        int mat = rem >> 2, rt = rem & 3;
        const int RB = br * BRO;
        const short* WTb = wb + (size_t)br * 6 * 4096 + (size_t)mat * 4096;
        f32x4 a4[4];
        #pragma unroll
        for (int c = 0; c < 4; ++c) { a4[c][0] = a4[c][1] = a4[c][2] = a4[c][3] = 0.f; }
        #pragma unroll
        for (int ks = 0; ks < 2; ++ks) {
            bf16x8 xa = *(const bf16x8*)&sm[RB + XB + swz(16 * rt + lo, 32 * ks + 8 * hg)];
            #pragma unroll
            for (int c = 0; c < 4; ++c) {
                bf16x8 bb = *(const bf16x8*)(WTb + (16 * c + lo) * 64 + 32 * ks + 8 * hg);
                a4[c] = MFMA(xa, bb, a4[c]);
            }
        }
        if (mat == 0) {
            #pragma unroll
            for (int c = 0; c < 4; ++c)
                #pragma unroll
                for (int r = 0; r < 4; ++r) {
                    int row = 16 * rt + 4 * hg + r;
                    if (row < 52)
                        sm[RB + QB + swz(row, 16 * c + lo)] = f2bf(a4[c][r] * 0.35355339059327378f);
                }
        } else if (mat == 1) {
            #pragma unroll
            for (int c = 0; c < 4; ++c)
                #pragma unroll
                for (int r = 0; r < 4; ++r) {
                    int row = 16 * rt + 4 * hg + r;
                    if (row < 52) sm[RB + KB + swz(row, 16 * c + lo)] = f2bf(a4[c][r]);
                }
        } else {
            #pragma unroll
            for (int c = 0; c < 4; ++c)
                #pragma unroll
                for (int r = 0; r < 4; ++r) {
                    int row = 16 * rt + 4 * hg + r, col = 16 * c + lo;
                    sm[RB + VBT + swz(col, row)] = (row < 50) ? f2bf(a4[c][r]) : (short)0;
                }
        }
    }
    __syncthreads();

    int svl = (lane < 50) ? seqi[lane] : 0;
    int cnt = (int)__popcll(__ballot(svl > 0));
    float msel[4][4];
    #pragma unroll
    for (int mt = 0; mt < 4; ++mt) {
        #pragma unroll
        for (int r = 0; r < 4; ++r) {
            int m = 16 * mt + 4 * hg + r;
            msel[mt][r] = (m < 50) ? ((seqi[m] > 0) ? 0.f : -1e9f) : -3.0e38f;
        }
    }

    bf16x8 zf;
    #pragma unroll
    for (int i = 0; i < 8; ++i) zf[i] = 0;

    // ---- attention: wave w = head w, both branches; ctx kept in registers ----
    f32x4 ctx2[2][4];
    const int hd = w;
    const int pbase = PB + (w << 10);
    #pragma unroll
    for (int br = 0; br < 2; ++br) {
        const int RB = br * BRO;
        bf16x8 ka[4], qf[4];
        #pragma unroll
        for (int t = 0; t < 4; ++t) {
            ka[t] = zf; qf[t] = zf;
            if (hg == 0) {
                ka[t] = *(const bf16x8*)&sm[RB + KB + swz(16 * t + lo, hd * 8)];
                qf[t] = *(const bf16x8*)&sm[RB + QB + swz(16 * t + lo, hd * 8)];
            }
        }
        f32x4 s[4][4];
        __builtin_amdgcn_s_setprio(1);
        #pragma unroll
        for (int mt = 0; mt < 4; ++mt) {
            #pragma unroll
            for (int c = 0; c < 4; ++c) {
                f32x4 z; z[0] = z[1] = z[2] = z[3] = 0.f;
                s[mt][c] = MFMA(ka[mt], qf[c], z);
            }
        }
        __builtin_amdgcn_s_setprio(0);
        #pragma unroll
        for (int mt = 0; mt < 4; ++mt) {
            #pragma unroll
            for (int r = 0; r < 4; ++r) {
                float ms = msel[mt][r];
                bool valid = (ms == 0.f);
                #pragma unroll
                for (int c = 0; c < 4; ++c) s[mt][c][r] = valid ? s[mt][c][r] : ms;
            }
        }
        uint32_t pk[4][4][2];
        #pragma unroll
        for (int c = 0; c < 4; ++c) {
            float mx = -3.4e38f;
            #pragma unroll
            for (int mt = 0; mt < 4; ++mt) {
                #pragma unroll
                for (int r = 0; r < 4; ++r) mx = fmaxf(mx, s[mt][c][r]);
            }
            mx = fmaxf(mx, __shfl_xor(mx, 16));
            mx = fmaxf(mx, __shfl_xor(mx, 32));
            float den = 0.f;
            #pragma unroll
            for (int mt = 0; mt < 4; ++mt) {
                #pragma unroll
                for (int r = 0; r < 4; ++r) {
                    float e = __expf(s[mt][c][r] - mx);
                    s[mt][c][r] = e; den += e;
                }
            }
            den += __shfl_xor(den, 16);
            den += __shfl_xor(den, 32);
            float inv = 1.f / den;
            #pragma unroll
            for (int mt = 0; mt < 4; ++mt) {
                pk[mt][c][0] = pk2(s[mt][c][0] * inv, s[mt][c][1] * inv);
                pk[mt][c][1] = pk2(s[mt][c][2] * inv, s[mt][c][3] * inv);
            }
        }
        #pragma unroll
        for (int t = 0; t < 4; ++t) {
            ctx2[br][t][0] = ctx2[br][t][1] = ctx2[br][t][2] = ctx2[br][t][3] = 0.f;
        }
        __builtin_amdgcn_s_setprio(1);
        #pragma unroll
        for (int rt = 0; rt < 4; ++rt) {
            #pragma unroll
            for (int mt = 0; mt < 4; ++mt) {
                int m0 = 16 * mt + 4 * hg;
                int sa = pbase + (lo << 6) + (m0 ^ ((lo & 7) << 3));
                uint2 pv; pv.x = pk[mt][rt][0]; pv.y = pk[mt][rt][1];
                *(uint2*)&sm[sa] = pv;
            }
            #pragma unroll
            for (int ks = 0; ks < 2; ++ks) {
                int ra = pbase + (lo << 6) + ((32 * ks + 8 * hg) ^ ((lo & 7) << 3));
                bf16x8 af = *(const bf16x8*)&sm[ra];
                bf16x8 bfr = zf;
                if (lo < 8) bfr = *(const bf16x8*)&sm[RB + VBT + swz(hd * 8 + lo, 32 * ks + 8 * hg)];
                ctx2[br][rt] = MFMA(af, bfr, ctx2[br][rt]);
            }
        }
        __builtin_amdgcn_s_setprio(0);
    }
    __syncthreads();
    if (lo < 8) {
        #pragma unroll
        for (int br = 0; br < 2; ++br) {
            const int RB = br * BRO;
            #pragma unroll
            for (int rt = 0; rt < 4; ++rt) {
                #pragma unroll
                for (int r = 0; r < 4; ++r) {
                    int row = 16 * rt + 4 * hg + r;
                    if (row < 52) sm[RB + KB + swz(row, hd * 8 + lo)] = f2bf(ctx2[br][rt][r]);
                }
            }
        }
    }
    __syncthreads();

    // ---- epilogue: ALL 8 waves; waves 0-3 -> branch0 stripes, 4-7 -> branch1 ----
    {
        const int ebr = w >> 2, ws = w & 3;
        const int RB = ebr * BRO;
        const short* WT  = wb + (size_t)ebr * 6 * 4096;
        const float* bo  = bo_all + ebr * 64;
        const float* lnp = ln_all + ebr * 256;
        const float* ffb = ffb_all + ebr * 128;

        float g1[4], b1[4], g2[4], b2[4], boc[4], f1b[4], f2b[4];
        #pragma unroll
        for (int c = 0; c < 4; ++c) {
            int col = 16 * c + lo;
            g1[c] = lnp[col];        b1[c] = lnp[64 + col];
            g2[c] = lnp[128 + col];  b2[c] = lnp[192 + col];
            boc[c] = bo[col]; f1b[c] = ffb[col]; f2b[c] = ffb[64 + col];
        }

        f32x4 acc[4];
        #pragma unroll
        for (int c = 0; c < 4; ++c) { acc[c][0] = acc[c][1] = acc[c][2] = acc[c][3] = 0.f; }
        #pragma unroll
        for (int ks = 0; ks < 2; ++ks) {
            bf16x8 a = *(const bf16x8*)&sm[RB + KB + swz(16 * ws + lo, 32 * ks + 8 * hg)]; // ctx
            #pragma unroll
            for (int c = 0; c < 4; ++c) {
                bf16x8 bb = *(const bf16x8*)(WT + 3 * 4096 + (16 * c + lo) * 64 + 32 * ks + 8 * hg);
                acc[c] = MFMA(a, bb, acc[c]);
            }
        }
        float x1v[4][4];
        #pragma unroll
        for (int r = 0; r < 4; ++r) {
            int row = 16 * ws + 4 * hg + r;
            float t0 = bf2f(sm[RB + XB + swz(row, lo)])      + acc[0][r] + boc[0];
            float t1 = bf2f(sm[RB + XB + swz(row, 16 + lo)]) + acc[1][r] + boc[1];
            float t2 = bf2f(sm[RB + XB + swz(row, 32 + lo)]) + acc[2][r] + boc[2];
            float t3 = bf2f(sm[RB + XB + swz(row, 48 + lo)]) + acc[3][r] + boc[3];
            float s1 = t0 + t1 + t2 + t3;
            float q1 = t0 * t0 + t1 * t1 + t2 * t2 + t3 * t3;
            #pragma unroll
            for (int d = 1; d <= 8; d <<= 1) { s1 += __shfl_xor(s1, d); q1 += __shfl_xor(q1, d); }
            float mean = s1 * 0.015625f;
            float var = q1 * 0.015625f - mean * mean;
            float rin = rsqrtf(var + 1e-5f);
            float x0 = (t0 - mean) * rin * g1[0] + b1[0];
            float x1 = (t1 - mean) * rin * g1[1] + b1[1];
            float x2 = (t2 - mean) * rin * g1[2] + b1[2];
            float x3 = (t3 - mean) * rin * g1[3] + b1[3];
            x1v[0][r] = x0; x1v[1][r] = x1; x1v[2][r] = x2; x1v[3][r] = x3;
            if (row < 52) {
                sm[RB + QB + swz(row, lo)]      = f2bf(x0);
                sm[RB + QB + swz(row, 16 + lo)] = f2bf(x1);
                sm[RB + QB + swz(row, 32 + lo)] = f2bf(x2);
                sm[RB + QB + swz(row, 48 + lo)] = f2bf(x3);
            }
        }
        #pragma unroll
        for (int c = 0; c < 4; ++c) { acc[c][0] = acc[c][1] = acc[c][2] = acc[c][3] = 0.f; }
        #pragma unroll
        for (int ks = 0; ks < 2; ++ks) {
            bf16x8 a = *(const bf16x8*)&sm[RB + QB + swz(16 * ws + lo, 32 * ks + 8 * hg)];
            #pragma unroll
            for (int c = 0; c < 4; ++c) {
                bf16x8 bb = *(const bf16x8*)(WT + 4 * 4096 + (16 * c + lo) * 64 + 32 * ks + 8 * hg);
                acc[c] = MFMA(a, bb, acc[c]);
            }
        }
        #pragma unroll
        for (int c = 0; c < 4; ++c) {
            #pragma unroll
            for (int r = 0; r < 4; ++r) {
                int row = 16 * ws + 4 * hg + r;
                if (row < 52) sm[RB + KB + swz(row, 16 * c + lo)] = f2bf(fmaxf(acc[c][r] + f1b[c], 0.f));
            }
        }
        #pragma unroll
        for (int c = 0; c < 4; ++c) { acc[c][0] = acc[c][1] = acc[c][2] = acc[c][3] = 0.f; }
        #pragma unroll
        for (int ks = 0; ks < 2; ++ks) {
            bf16x8 a = *(const bf16x8*)&sm[RB + KB + swz(16 * ws + lo, 32 * ks + 8 * hg)];
            #pragma unroll
            for (int c = 0; c < 4; ++c) {
                bf16x8 bb = *(const bf16x8*)(WT + 5 * 4096 + (16 * c + lo) * 64 + 32 * ks + 8 * hg);
                acc[c] = MFMA(a, bb, acc[c]);
            }
        }
        float wv = (cnt > 0) ? 1.f / (float)cnt : 0.02f;
        float np[4] = {0.f, 0.f, 0.f, 0.f};
        #pragma unroll
        for (int r = 0; r < 4; ++r) {
            int row = 16 * ws + 4 * hg + r;
            float t0 = x1v[0][r] + acc[0][r] + f2b[0];
            float t1 = x1v[1][r] + acc[1][r] + f2b[1];
            float t2 = x1v[2][r] + acc[2][r] + f2b[2];
            float t3 = x1v[3][r] + acc[3][r] + f2b[3];
            float s1 = t0 + t1 + t2 + t3;
            float q1 = t0 * t0 + t1 * t1 + t2 * t2 + t3 * t3;
            #pragma unroll
            for (int d = 1; d <= 8; d <<= 1) { s1 += __shfl_xor(s1, d); q1 += __shfl_xor(q1, d); }
            float mean = s1 * 0.015625f;
            float var = q1 * 0.015625f - mean * mean;
            float rin = rsqrtf(var + 1e-5f);
            float wl = 0.f;
            if (row < 50) {
                int sv = seqi[row];
                wl = (cnt > 0) ? ((sv > 0) ? wv : 0.f) : wv;
            }
            np[0] += ((t0 - mean) * rin * g2[0] + b2[0]) * wl;
            np[1] += ((t1 - mean) * rin * g2[1] + b2[1]) * wl;
            np[2] += ((t2 - mean) * rin * g2[2] + b2[2]) * wl;
            np[3] += ((t3 - mean) * rin * g2[3] + b2[3]) * wl;
        }
        #pragma unroll
        for (int c = 0; c < 4; ++c) {
            np[c] += __shfl_xor(np[c], 16);
            np[c] += __shfl_xor(np[c], 32);
        }
        if (hg == 0) {
            #pragma unroll
            for (int c = 0; c < 4; ++c) nbuf[ebr][ws][16 * c + lo] = np[c];
        }
    }
    __syncthreads();
    if (tid < 64)
        nvec[0][tid] = nbuf[0][0][tid] + nbuf[0][1][tid] + nbuf[0][2][tid] + nbuf[0][3][tid];
    else if (tid < 128)
        nvec[1][tid - 64] = nbuf[1][0][tid - 64] + nbuf[1][1][tid - 64] +
                            nbuf[1][2][tid - 64] + nbuf[1][3][tid - 64];
    else if (tid == 128) nvec[0][64] = spread[(size_t)ib * 4 + 2] * (1.f / 86400.f);
    else if (tid == 129) nvec[0][65] = spread[(size_t)ib * 4 + 3] * (1.f / 86400.f);
    else if (tid == 130) nvec[1][64] = spread[(size_t)ib * 4 + 0];
    else if (tid == 131) nvec[1][65] = spread[(size_t)ib * 4 + 1];
    __syncthreads();
    if (tid < F2) {
        float a = 0.f;
        for (int k = 0; k < F2; ++k) a += nvec[0][k] * weight[k * F2 + tid];
        n_t[(size_t)b * F2 + tid] = a;
    } else if (tid >= 128 && tid < 128 + F2) {
        int col = tid - 128;
        float a = 0.f;
        for (int k = 0; k < F2; ++k) a += nvec[1][k] * weight2[k * F2 + col];
        n_s[(size_t)b * F2 + col] = a;
    }
}

// ---------------- gated fusion head: 4 batch elems per block, wave-local ----------------

__global__ __launch_bounds__(256) void k_fuse(
    const float* __restrict__ n_t, const float* __restrict__ n_s,
    const float* __restrict__ l1W, const float* __restrict__ l1b,
    const float* __restrict__ l2W, const float* __restrict__ l2b,
    const float* __restrict__ outW, const float* __restrict__ outb,
    float* __restrict__ out)
{
    const int w = threadIdx.x >> 6, j = threadIdx.x & 63;
    const int b = blockIdx.x * 4 + w;
    __shared__ float et[4][F2], es[4][F2], fused[4][F2];
    for (int t = j; t < F2; t += 64) { et[w][t] = n_t[(size_t)b * F2 + t]; es[w][t] = n_s[(size_t)b * F2 + t]; }
    float sl[2];
    for (int s = 0; s < 2; ++s) {
        const float* e = s ? es[w] : et[w];
        float part = 0.f;
        for (int t = j; t < F2; t += 64) {
            float acc = l1b[t];
            for (int k = 0; k < F2; ++k) acc += e[k] * l1W[k * F2 + t];
            part += tanhf(acc) * l2W[t];
        }
        part = wsum(part);
        sl[s] = part + l2b[0];
    }
    float mx = fmaxf(sl[0], sl[1]);
    float e0 = __expf(sl[0] - mx), e1 = __expf(sl[1] - mx);
    float inv = 1.f / (e0 + e1);
    float sc0 = e0 * inv, sc1 = e1 * inv;
    for (int t = j; t < F2; t += 64) fused[w][t] = sc0 * et[w][t] + sc1 * es[w][t];
    float p0 = 0.f, p1 = 0.f;
    for (int t = j; t < F2; t += 64) {
        p0 += fused[w][t] * outW[t * 2 + 0];
        p1 += fused[w][t] * outW[t * 2 + 1];
    }
    p0 = wsum(p0); p1 = wsum(p1);
    if (j == 0) {
        float l0 = p0 + outb[0], l1v = p1 + outb[1];
        float m = fmaxf(l0, l1v);
        float lse = m + logf(__expf(l0 - m) + __expf(l1v - m));
        out[(size_t)b * 2 + 0] = l0 - lse;
        out[(size_t)b * 2 + 1] = l1v - lse;
    }
}

extern "C" void kernel_launch(void* const* d_in, const int* in_sizes, int n_in,
                              void* d_out, int out_size, void* d_ws, size_t ws_size,
                              hipStream_t stream)
{
    (void)in_sizes; (void)n_in; (void)out_size; (void)ws_size;
    const float* user_emb = (const float*)d_in[0];
    const float* cen_emb  = (const float*)d_in[1];
    const float* time_emb = (const float*)d_in[2];
    const float* pos_emb  = (const float*)d_in[3];
    const float* inf_emb  = (const float*)d_in[4];
    const float* w1       = (const float*)d_in[5];
    const float* w2       = (const float*)d_in[6];
    const float* weight   = (const float*)d_in[10];
    const float* weight2  = (const float*)d_in[11];
    const float* l1W      = (const float*)d_in[12];
    const float* l1b      = (const float*)d_in[13];
    const float* l2W      = (const float*)d_in[14];
    const float* l2b      = (const float*)d_in[15];
    const float* outW     = (const float*)d_in[16];
    const float* outb     = (const float*)d_in[17];
    const float* qkv      = (const float*)d_in[18];
    const float* Wo       = (const float*)d_in[19];
    const float* bo       = (const float*)d_in[20];
    const float* lnp      = (const float*)d_in[21];
    const float* ffW      = (const float*)d_in[22];
    const float* ffb      = (const float*)d_in[23];
    const float* spread   = (const float*)d_in[25];
    const int* data_idx   = (const int*)d_in[26];
    const int* seq        = (const int*)d_in[27];
    const int* timestamps = (const int*)d_in[28];
    const int* user_level = (const int*)d_in[29];
    const int* useq       = (const int*)d_in[30];
    const int* user_inf   = (const int*)d_in[31];
    const int* user_cen   = (const int*)d_in[32];

    // workspace layout (ushort units)
    unsigned short* wbt = (unsigned short*)d_ws;          // 14*4096 = 57,344
    unsigned short* xb  = wbt + 57344;                    // 6,400,000
    unsigned short* em  = xb + 6400000;                   // 1,280,000
    unsigned short* e2b = em + 1280000;                   // 1,280,000
    unsigned short* nbm = e2b + 1280000;                  // 3,276,800
    float* n_t = (float*)(nbm + 3276800);                 // 67,584 f32
    float* n_s = n_t + 67584;                             // 67,584 f32
    float* out = (float*)d_out;

    k_prep<<<224, 256, 0, stream>>>(qkv, Wo, ffW, w2, w1, (short*)wbt);
    k_hgnn1m<<<1563, 256, 0, stream>>>(user_emb, cen_emb, user_cen,
                                       (const short*)wbt + 13 * 4096, xb);
    k_edge_gather<<<5000, 256, 0, stream>>>(xb, seq, em);
    k_gemm_edge<<<313, 256, 0, stream>>>(em, (const short*)wbt + 12 * 4096, e2b);
    k_nodem<<<12800, 256, 0, stream>>>(e2b, seq, useq, data_idx, nbm);
    k_tblock2<<<1024, 512, 0, stream>>>(nbm, seq, data_idx, timestamps, user_inf,
                                        user_level, time_emb, inf_emb, pos_emb,
                                        (const short*)wbt, bo, lnp, ffb, spread,
                                        weight, weight2, n_t, n_s);
    k_fuse<<<256, 256, 0, stream>>>(n_t, n_s, l1W, l1b, l2W, l2b, outW, outb, out);
}